// Round 1
// 146.116 us; speedup vs baseline: 1.0397x; 1.0397x over previous
//
#include <hip/hip_runtime.h>
#include <math.h>

// Problem constants
#define NN 512
#define DD 512
#define NPAIRS 130816            // 512*511/2
#define TYPES_OFF 0              // [P,10] floats
#define ARGMAX_OFF 1308160      // [P] floats
#define STRENGTH_OFF 1438976    // [P] floats

// fp32 fast-path argmax guard: recompute logits in fp64 when fp32 top-2 gap
// is below this. fp32-path worst-case abs error ~5e-5; realistic rms ~1e-6.
#define GAP_THRESH 2.5e-4f

// ws layout (byte offsets) — K-split-2 partials, summed in pair staging:
//   ca0  double[512][512] @ 0         (bias cb1 folded; k 0..255 of F@cw1[:D])
//   ca1  double[512][512] @ 2097152   (k 256..511)
//   cb0  double[512][512] @ 4194304   (F@cw1[D:], k 0..255)
//   cbp1 double[512][512] @ 6291456   (k 256..511)
//   sa0  float [512][256] @ 8388608   (bias sb1 folded)
//   sa1  float [512][256] @ 8912896
//   sb0  float [512][256] @ 9437184
//   sbp1 float [512][256] @ 9961472
// total 10,485,760 bytes

__device__ __forceinline__ void fma64_step(
    const float4& a0, const float4& a1,
    const float4& b0, const float4& b1, const float4& b2, const float4& b3,
    double acc[2][4])
{
    const float av[2][4] = {{a0.x,a0.y,a0.z,a0.w},{a1.x,a1.y,a1.z,a1.w}};
    const float bv[4][4] = {{b0.x,b0.y,b0.z,b0.w},{b1.x,b1.y,b1.z,b1.w},
                            {b2.x,b2.y,b2.z,b2.w},{b3.x,b3.y,b3.z,b3.w}};
    #pragma unroll
    for (int kk = 0; kk < 4; ++kk) {
        double ad0 = (double)av[0][kk], ad1 = (double)av[1][kk];
        #pragma unroll
        for (int c = 0; c < 4; ++c) {
            double bd = (double)bv[kk][c];
            acc[0][c] = fma(ad0, bd, acc[0][c]);
            acc[1][c] = fma(ad1, bd, acc[1][c]);
        }
    }
}

__device__ __forceinline__ void fma32_step(
    const float4& a0, const float4& a1,
    const float4& b0, const float4& b1, const float4& b2, const float4& b3,
    float acc[2][4])
{
    const float av[2][4] = {{a0.x,a0.y,a0.z,a0.w},{a1.x,a1.y,a1.z,a1.w}};
    const float bv[4][4] = {{b0.x,b0.y,b0.z,b0.w},{b1.x,b1.y,b1.z,b1.w},
                            {b2.x,b2.y,b2.z,b2.w},{b3.x,b3.y,b3.z,b3.w}};
    #pragma unroll
    for (int kk = 0; kk < 4; ++kk) {
        #pragma unroll
        for (int c = 0; c < 4; ++c) {
            acc[0][c] = fmaf(av[0][kk], bv[kk][c], acc[0][c]);
            acc[1][c] = fmaf(av[1][kk], bv[kk][c], acc[1][c]);
        }
    }
}

// Barrier-free, LDS-free, atomic-free projection GEMM.
// Wave = 8m x 64n tile, thread = 2m x 4n, K-split 2 into partial buffers.
// wid [0,2048):    fp64 classifier (out 512x1024)
// wid [2048,3072): fp32 strength   (out 512x512)
__global__ __launch_bounds__(256, 4) void proj_kernel(
    const float* __restrict__ F, const float* __restrict__ cw1,
    const float* __restrict__ sw1,
    const float* __restrict__ cb1, const float* __restrict__ sb1,
    double* __restrict__ ca0, double* __restrict__ ca1,
    double* __restrict__ cb0, double* __restrict__ cbp1,
    float* __restrict__ sa0, float* __restrict__ sa1,
    float* __restrict__ sb0, float* __restrict__ sbp1)
{
    const int t = threadIdx.x;
    const int wid  = blockIdx.x * 4 + (t >> 6);
    const int lane = t & 63;
    const int mg = lane >> 4;              // 0..3  (2-row group)
    const int nq = lane & 15;              // 0..15 (4-col group)

    if (wid < 2048) {
        // ---------------- fp64 classifier projection ----------------
        const int z  = wid & 1;            // K half
        const int r  = wid >> 1;           // 0..1023
        const int nt = r & 15;             // 64-col tile over 1024
        const int mt = r >> 4;             // 0..63
        const int m0 = mt * 8;
        const int n  = nt * 64;
        const float* W = (n < 512) ? cw1 : cw1 + 512 * 512;
        const int n0   = (n < 512) ? n : n - 512;
        double* outp   = (n < 512) ? (z ? ca1 : ca0) : (z ? cbp1 : cb0);
        const bool addbias = (z == 0) && (n < 512);

        const int row0 = m0 + mg * 2;
        const int col0 = n0 + nq * 4;
        const float* pa0 = F + row0 * 512 + z * 256;
        const float* pa1 = pa0 + 512;
        const float* pb  = W + (z * 256) * 512 + col0;

        double acc[2][4];
        #pragma unroll
        for (int rr = 0; rr < 2; ++rr)
            #pragma unroll
            for (int cc = 0; cc < 4; ++cc) acc[rr][cc] = 0.0;

        float4 a0 = *(const float4*)(pa0);
        float4 a1 = *(const float4*)(pa1);
        float4 b0 = *(const float4*)(pb);
        float4 b1 = *(const float4*)(pb + 512);
        float4 b2 = *(const float4*)(pb + 1024);
        float4 b3 = *(const float4*)(pb + 1536);
        for (int s = 0; s < 63; ++s) {     // 64 k4-steps, software-pipelined
            float4 na0 = *(const float4*)(pa0 + (s + 1) * 4);
            float4 na1 = *(const float4*)(pa1 + (s + 1) * 4);
            const float* nb = pb + (s + 1) * 2048;
            float4 nb0 = *(const float4*)(nb);
            float4 nb1 = *(const float4*)(nb + 512);
            float4 nb2 = *(const float4*)(nb + 1024);
            float4 nb3 = *(const float4*)(nb + 1536);
            fma64_step(a0, a1, b0, b1, b2, b3, acc);
            a0 = na0; a1 = na1; b0 = nb0; b1 = nb1; b2 = nb2; b3 = nb3;
        }
        fma64_step(a0, a1, b0, b1, b2, b3, acc);

        #pragma unroll
        for (int rr = 0; rr < 2; ++rr) {
            double v[4];
            #pragma unroll
            for (int cc = 0; cc < 4; ++cc) {
                v[cc] = acc[rr][cc];
                if (addbias) v[cc] += (double)cb1[col0 + cc];
            }
            double* dst = outp + (row0 + rr) * 512 + col0;
            *(double2*)(dst + 0) = make_double2(v[0], v[1]);
            *(double2*)(dst + 2) = make_double2(v[2], v[3]);
        }
    } else {
        // ---------------- fp32 strength projection ----------------
        const int w2 = wid - 2048;
        const int z  = w2 & 1;
        const int r  = w2 >> 1;            // 0..511
        const int nt = r & 7;              // 64-col tile over 512
        const int mt = r >> 3;             // 0..63
        const int m0 = mt * 8;
        const int n  = nt * 64;
        const float* W = (n < 256) ? sw1 : sw1 + 512 * 256;
        const int n0   = (n < 256) ? n : n - 256;
        float* outp    = (n < 256) ? (z ? sa1 : sa0) : (z ? sbp1 : sb0);
        const bool addbias = (z == 0) && (n < 256);

        const int row0 = m0 + mg * 2;
        const int col0 = n0 + nq * 4;
        const float* pa0 = F + row0 * 512 + z * 256;
        const float* pa1 = pa0 + 512;
        const float* pb  = W + (z * 256) * 256 + col0;

        float acc[2][4];
        #pragma unroll
        for (int rr = 0; rr < 2; ++rr)
            #pragma unroll
            for (int cc = 0; cc < 4; ++cc) acc[rr][cc] = 0.f;

        float4 a0 = *(const float4*)(pa0);
        float4 a1 = *(const float4*)(pa1);
        float4 b0 = *(const float4*)(pb);
        float4 b1 = *(const float4*)(pb + 256);
        float4 b2 = *(const float4*)(pb + 512);
        float4 b3 = *(const float4*)(pb + 768);
        for (int s = 0; s < 63; ++s) {
            float4 na0 = *(const float4*)(pa0 + (s + 1) * 4);
            float4 na1 = *(const float4*)(pa1 + (s + 1) * 4);
            const float* nb = pb + (s + 1) * 1024;
            float4 nb0 = *(const float4*)(nb);
            float4 nb1 = *(const float4*)(nb + 256);
            float4 nb2 = *(const float4*)(nb + 512);
            float4 nb3 = *(const float4*)(nb + 768);
            fma32_step(a0, a1, b0, b1, b2, b3, acc);
            a0 = na0; a1 = na1; b0 = nb0; b1 = nb1; b2 = nb2; b3 = nb3;
        }
        fma32_step(a0, a1, b0, b1, b2, b3, acc);

        #pragma unroll
        for (int rr = 0; rr < 2; ++rr) {
            float4 v = make_float4(acc[rr][0], acc[rr][1], acc[rr][2], acc[rr][3]);
            if (addbias) {
                v.x += sb1[col0 + 0]; v.y += sb1[col0 + 1];
                v.z += sb1[col0 + 2]; v.w += sb1[col0 + 3];
            }
            *(float4*)(outp + (row0 + rr) * 256 + col0) = v;
        }
    }
}

// Pair phase: block = 8x8 pair tile, 4 waves = 4 K-quarters, LDS combine.
// Grid: 2080 triangular tiles. Staging sums the two fp64 K-split partials and
// CONVERTS TO FP32 — inner loop runs at 2 cyc/instr instead of fp64's 4.
// Argmax exactness is preserved by an fp64 cooperative recheck of pairs whose
// fp32 top-2 logit gap is < GAP_THRESH (rare: ~1% of pairs).
// NOTE: inner loops MUST stay scalar-read + partial-unroll (R3 form). Full
// unroll or wider per-iter weight footprints -> VGPR explosion -> lg[] spills.
__global__ __launch_bounds__(256, 4) void pair_kernel(
    const double* __restrict__ ca0, const double* __restrict__ ca1,
    const double* __restrict__ cb0, const double* __restrict__ cbp1,
    const float* __restrict__ sa0, const float* __restrict__ sa1,
    const float* __restrict__ sb0, const float* __restrict__ sbp1,
    const float* __restrict__ cw2, const float* __restrict__ cb2,
    const float* __restrict__ sw2, const float* __restrict__ sb2,
    float* __restrict__ out)
{
    // triangular tile decode: S(bi) = bi*(129-bi)/2
    const int b = blockIdx.x;
    int bi = (int)floorf((129.0f - sqrtf(16641.0f - 8.0f * (float)b)) * 0.5f);
    while ((bi + 1) * (129 - (bi + 1)) / 2 <= b) ++bi;
    while (bi * (129 - bi) / 2 > b) --bi;
    const int bj = bi + (b - bi * (129 - bi) / 2);
    const int i0 = bi * 8, j0 = bj * 8;

    const int t = threadIdx.x;
    const int q  = t >> 6;                               // K-quarter = wave id
    const int qu = __builtin_amdgcn_readfirstlane(q);    // wave-uniform -> s_load bases
    const int l = t & 63;
    const int pi = l >> 3, pj = l & 7;
    const int i = i0 + pi, j = j0 + pj;

    __shared__ __align__(16) float smem[4352];      // 17408 B
    float* sSa = smem;                              // [4*8][68] strength stage
    float* sSb = smem + 2176;
    float* sA  = smem;                              // [4*8][68] classifier stage
    float* sB  = smem + 2176;
    float* lgbuf = smem;                            // [3][64][10]
    float* stbuf = smem + 1920;                     // [3][64]

    // ---------------- strength (fp32), K=64 per quarter ----------------
    #pragma unroll
    for (int u = 0; u < 4; ++u) {
        int idx = u * 256 + t;
        int kq  = idx & 15;
        int row = (idx >> 4) & 7;
        int qq  = (idx >> 7) & 3;
        int arr = idx >> 9;
        int off = (arr ? (j0 + row) : (i0 + row)) * 256 + qq * 64 + kq * 4;
        const float* s0 = arr ? sb0 : sa0;
        const float* s1 = arr ? sbp1 : sa1;
        float4 v0 = *(const float4*)(s0 + off);
        float4 v1 = *(const float4*)(s1 + off);
        float4 v = make_float4(v0.x + v1.x, v0.y + v1.y, v0.z + v1.z, v0.w + v1.w);
        float* dst = (arr ? sSb : sSa) + (qq * 8 + row) * 68 + kq * 4;
        *(float4*)dst = v;
    }
    __syncthreads();
    float accs = 0.f;
    {
        const float* sw2q = sw2 + qu * 64;
        const float* ra = sSa + (q * 8 + pi) * 68;
        const float* rb = sSb + (q * 8 + pj) * 68;
        #pragma unroll 16
        for (int kk = 0; kk < 64; ++kk) {
            float h = fmaxf(ra[kk] + rb[kk], 0.f);
            accs = fmaf(h, sw2q[kk], accs);
        }
    }

    // ---------------- classifier (fp32 fast path), K=128 per quarter ----------------
    float lg[10];
    #pragma unroll
    for (int c = 0; c < 10; ++c) lg[c] = 0.f;

    for (int rnd = 0; rnd < 2; ++rnd) {
        __syncthreads();   // prior reads of sA/sB (or sSa/sSb) done
        // stage 64 k per quarter: sum fp64 K-split partials, convert to fp32
        #pragma unroll
        for (int u = 0; u < 4; ++u) {
            int idx = u * 256 + t;
            int kq  = idx & 15;               // 16 groups of 4 k
            int row = (idx >> 4) & 7;
            int qq  = (idx >> 7) & 3;
            int arr = idx >> 9;
            int off = (arr ? (j0 + row) : (i0 + row)) * 512 + qq * 128 + rnd * 64 + kq * 4;
            const double* d0 = arr ? cb0 : ca0;
            const double* d1 = arr ? cbp1 : ca1;
            double2 x0 = *(const double2*)(d0 + off);
            double2 x1 = *(const double2*)(d0 + off + 2);
            double2 y0 = *(const double2*)(d1 + off);
            double2 y1 = *(const double2*)(d1 + off + 2);
            float4 v = make_float4((float)(x0.x + y0.x), (float)(x0.y + y0.y),
                                   (float)(x1.x + y1.x), (float)(x1.y + y1.y));
            float* dst = (arr ? sB : sA) + (qq * 8 + row) * 68 + kq * 4;
            *(float4*)dst = v;
        }
        __syncthreads();
        const float* ra = sA + (q * 8 + pi) * 68;
        const float* rb = sB + (q * 8 + pj) * 68;
        const float* wr = cw2 + (qu * 128 + rnd * 64) * 10;
        #pragma unroll 8
        for (int kk = 0; kk < 64; ++kk) {
            float h = fmaxf(ra[kk] + rb[kk], 0.f);
            const float* w = wr + kk * 10;
            #pragma unroll
            for (int c = 0; c < 10; ++c) lg[c] = fmaf(h, w[c], lg[c]);
        }
    }

    // ---------------- combine via LDS ----------------
    __syncthreads();
    if (q > 0) {
        float* dst = lgbuf + ((q - 1) * 64 + l) * 10;
        #pragma unroll
        for (int c = 0; c < 10; ++c) dst[c] = lg[c];
        stbuf[(q - 1) * 64 + l] = accs;
    }
    __syncthreads();
    if (q == 0) {
        #pragma unroll
        for (int w = 0; w < 3; ++w) {
            const float* srcb = lgbuf + (w * 64 + l) * 10;
            #pragma unroll
            for (int c = 0; c < 10; ++c) lg[c] += srcb[c];
        }
        float st = accs + stbuf[l] + stbuf[64 + l] + stbuf[128 + l] + sb2[0];

        #pragma unroll
        for (int c = 0; c < 10; ++c) lg[c] += cb2[c];

        // fp32 argmax + top-2 gap
        float mx = lg[0], mx2 = -3.0e38f; int am2 = 0;
        #pragma unroll
        for (int c = 1; c < 10; ++c) {
            if (lg[c] > mx) { mx2 = mx; mx = lg[c]; am2 = c; }
            else if (lg[c] > mx2) mx2 = lg[c];
        }

        // fp64 cooperative recheck of near-tied pairs (rare). Whole q0-wave
        // recomputes one pair's logits from the fp64 partials: 8 k's per lane,
        // butterfly-reduce, fp64 argmax overrides the flagged lane's am2.
        unsigned long long m = __ballot((j > i) && (mx - mx2 < GAP_THRESH));
        while (m) {
            const int s = __ffsll((unsigned long long)m) - 1; m &= (m - 1);
            const int si = i0 + (s >> 3), sj = j0 + (s & 7);
            double part[10];
            #pragma unroll
            for (int c = 0; c < 10; ++c) part[c] = 0.0;
            const int kb = l * 8;
            #pragma unroll 2
            for (int kk = 0; kk < 8; ++kk) {
                const int k = kb + kk;
                double h = fmax(ca0[si * 512 + k] + ca1[si * 512 + k]
                              + cb0[sj * 512 + k] + cbp1[sj * 512 + k], 0.0);
                const float* w = cw2 + k * 10;
                #pragma unroll
                for (int c = 0; c < 10; ++c) part[c] = fma(h, (double)w[c], part[c]);
            }
            #pragma unroll
            for (int off = 32; off > 0; off >>= 1) {
                #pragma unroll
                for (int c = 0; c < 10; ++c) part[c] += __shfl_xor(part[c], off, 64);
            }
            double bmx = part[0] + (double)cb2[0]; int ba = 0;
            #pragma unroll
            for (int c = 1; c < 10; ++c) {
                double v = part[c] + (double)cb2[c];
                if (v > bmx) { bmx = v; ba = c; }   // first-max == np.argmax
            }
            if (l == s) am2 = ba;
        }

        float tf[10]; float ssum = 0.f;
        #pragma unroll
        for (int c = 0; c < 10; ++c) { tf[c] = lg[c] - mx; ssum += __expf(tf[c]); }
        float ls = __logf(ssum);

        if (j > i) {
            const int p = i * 511 - (i * (i - 1)) / 2 + (j - i - 1);
            float* tp = out + TYPES_OFF + p * 10;
            #pragma unroll
            for (int c = 0; c < 10; ++c) tp[c] = tf[c] - ls;
            out[ARGMAX_OFF + p] = (float)am2;
            out[STRENGTH_OFF + p] = 1.0f / (1.0f + __expf(-st));
        }
    }
}

extern "C" void kernel_launch(void* const* d_in, const int* in_sizes, int n_in,
                              void* d_out, int out_size, void* d_ws, size_t ws_size,
                              hipStream_t stream) {
    const float* F   = (const float*)d_in[0];
    const float* cw1 = (const float*)d_in[1];
    const float* cb1 = (const float*)d_in[2];
    const float* cw2 = (const float*)d_in[3];
    const float* cb2 = (const float*)d_in[4];
    const float* sw1 = (const float*)d_in[5];
    const float* sb1 = (const float*)d_in[6];
    const float* sw2 = (const float*)d_in[7];
    const float* sb2 = (const float*)d_in[8];
    float* out = (float*)d_out;

    char* ws = (char*)d_ws;
    double* ca0  = (double*)(ws);
    double* ca1  = (double*)(ws + 2097152);
    double* cb0  = (double*)(ws + 4194304);
    double* cbp1 = (double*)(ws + 6291456);
    float*  sa0  = (float*)(ws + 8388608);
    float*  sa1  = (float*)(ws + 8912896);
    float*  sb0  = (float*)(ws + 9437184);
    float*  sbp1 = (float*)(ws + 9961472);

    hipLaunchKernelGGL(proj_kernel, dim3(768), dim3(256), 0, stream,
                       F, cw1, sw1, cb1, sb1,
                       ca0, ca1, cb0, cbp1, sa0, sa1, sb0, sbp1);
    hipLaunchKernelGGL(pair_kernel, dim3(2080), dim3(256), 0, stream,
                       ca0, ca1, cb0, cbp1, sa0, sa1, sb0, sbp1,
                       cw2, cb2, sw2, sb2, out);
}